// Round 12
// baseline (31.269 us; speedup 1.0000x reference)
//
#include <hip/hip_runtime.h>

#define NT   256
#define NBLK 768
#define PPI  (NBLK * NT / 4)   // problems per pipeline iteration = 49152

// ============================================================================
// Persistent pipelined kernel, v2. 4 lanes per problem (quad slot q = tid&3
// owns global rows {2q,2q+1}); DPP quad_perm broadcasts; packed v_pk_fma_f32.
// NEXT problem's A (12 KB/wave) prefetched into a per-wave-private LDS stage
// buffer via global_load_lds, issued BEFORE the current ~2000-cycle compute.
//
// R12 vs R11 (29.1us, correct but 2 waves/SIMD): alpha3 moved from LDS into
// registers (+16 VGPR, live ~86 << 128) -> LDS is stage-only 48KB/block ->
// 3 blocks/CU -> 3 waves/SIMD (+50% occupancy). NBLK=768 fills exactly
// 3 blocks/CU x 256 CU; NI=3 iterations covers B=131072.
// Fence discipline identical to the proven R11: vmcnt(0)+sched_barrier before
// consuming staged data; lgkmcnt(0)+sched_barrier before re-issuing DMAs
// into the same slots. Stage buffer wave-private -> no __syncthreads.
// ============================================================================

typedef float v2f __attribute__((ext_vector_type(2)));

template <int O>
__device__ __forceinline__ float qb(float x) {
    return __int_as_float(__builtin_amdgcn_mov_dpp(
        __float_as_int(x), O * 0x55, 0xF, 0xF, true));
}
template <int O>
__device__ __forceinline__ v2f qb2(v2f y) {
    v2f r;
    r.x = qb<O>(y.x);
    r.y = qb<O>(y.y);
    return r;
}
__device__ __forceinline__ v2f pkfma(v2f a, v2f b, v2f c) {
    return __builtin_elementwise_fma(a, b, c);   // -> v_pk_fma_f32
}

// acc(2x8, col-pairs) += SGN * X(2x8) @ Y, contribution from Y's global rows
// {2O, 2O+1} (held by quad slot O as its local rows 0,1).
template <int SGN, int O>
__device__ __forceinline__ void mm4_o(v2f (&acc)[8], const v2f (&X)[8],
                                      const v2f (&Y)[8]) {
#pragma unroll
    for (int s = 0; s < 2; ++s) {            // global k = 2O + s
        v2f w2[4];
#pragma unroll
        for (int jj = 0; jj < 4; ++jj) w2[jj] = qb2<O>(Y[s * 4 + jj]);
#pragma unroll
        for (int r = 0; r < 2; ++r) {
            const float x0 = (s == 0) ? X[r * 4 + O].x : X[r * 4 + O].y;
            const float xs = (SGN > 0) ? x0 : -x0;
            const v2f xx = {xs, xs};
#pragma unroll
            for (int jj = 0; jj < 4; ++jj)
                acc[r * 4 + jj] = pkfma(xx, w2[jj], acc[r * 4 + jj]);
        }
    }
}
template <int SGN>
__device__ __forceinline__ void mm4(v2f (&acc)[8], const v2f (&X)[8],
                                    const v2f (&Y)[8]) {
    mm4_o<SGN, 0>(acc, X, Y);
    mm4_o<SGN, 1>(acc, X, Y);
    mm4_o<SGN, 2>(acc, X, Y);
    mm4_o<SGN, 3>(acc, X, Y);
}

// One DMA chunk: 64 lanes x 16B -> LDS slot (lane-linear), offset literal 0.
__device__ __forceinline__ void glds1(const float4* g, float4* l) {
    __builtin_amdgcn_global_load_lds(
        (const __attribute__((address_space(1))) void*)g,
        (__attribute__((address_space(3))) void*)l,
        16, 0, 0);
}

// Stage all 12 chunks of this wave's next 16 problems.
// g = A4 + p*48 + q*4 (per-lane); slot m*4+c <- g + m*16 + c.
__device__ __forceinline__ void stage_all(const float4* g, float4* l) {
    glds1(g + 0,  l + 0 * 64);   glds1(g + 1,  l + 1 * 64);
    glds1(g + 2,  l + 2 * 64);   glds1(g + 3,  l + 3 * 64);
    glds1(g + 16, l + 4 * 64);   glds1(g + 17, l + 5 * 64);
    glds1(g + 18, l + 6 * 64);   glds1(g + 19, l + 7 * 64);
    glds1(g + 32, l + 8 * 64);   glds1(g + 33, l + 9 * 64);
    glds1(g + 34, l + 10 * 64);  glds1(g + 35, l + 11 * 64);
}

__global__ __launch_bounds__(NT)
void magnus6_kernel(const float* __restrict__ A,
                    const float* __restrict__ hp,
                    const float* __restrict__ y0,
                    float* __restrict__ out,
                    int B, int NI)
{
    __shared__ float4 stage[4][12][64];   // per-wave stage buffers, 48 KB only

    const int tx    = threadIdx.x;
    const int w     = tx >> 6;            // wave in block
    const int lane  = tx & 63;
    const int q     = tx & 3;             // quad slot: owns rows 2q, 2q+1
    const int pslot = blockIdx.x * (NT / 4) + (tx >> 2);

    const float h    = hp[0];
    const float c_a2 = h * 1.2909944487358056f;   // h*sqrt(15)/3
    const float c_a3 = h * (10.0f / 3.0f);
    const float c_m  = 20.0f / 3.0f;

    const float4* __restrict__ A4 = reinterpret_cast<const float4*>(A);
    float4* sb = &stage[w][0][0];

    // ---- prologue: stage iteration 0 ----
    {
        const int pn = pslot;
        const int pc = pn < B ? pn : B - 1;
        stage_all(A4 + (size_t)pc * 48 + q * 4, sb);
    }

    for (int n = 0; n < NI; ++n) {
        const int p   = n * PPI + pslot;
        const int pcl = p < B ? p : B - 1;

        // wait for this iteration's staged data; fence per rule 18
        asm volatile("s_waitcnt vmcnt(0)" ::: "memory");
        __builtin_amdgcn_sched_barrier(0);

        const float2 y0v =
            *reinterpret_cast<const float2*>(y0 + (size_t)pcl * 8 + 2 * q);

        v2f R1[8];   // alpha1 -> Omega0 -> Omega
        v2f R2[8];   // alpha2 -> Q
        v2f R3[8];   // C1 -> T' -> P'
        v2f A3r[8];  // alpha3 (registers, not LDS)

        // ---- alpha build from staged LDS ----
#pragma unroll
        for (int c = 0; c < 4; ++c) {
            float4 v1 = stage[w][c][lane];
            float4 v2 = stage[w][4 + c][lane];
            float4 v3 = stage[w][8 + c][lane];
            const int b = (c >> 1) * 4 + (c & 1) * 2;
            v2f A1lo = {v1.x, v1.y}, A1hi = {v1.z, v1.w};
            v2f A2lo = {v2.x, v2.y}, A2hi = {v2.z, v2.w};
            v2f A3lo = {v3.x, v3.y}, A3hi = {v3.z, v3.w};
            v2f al1lo = h * A2lo, al1hi = h * A2hi;            // alpha1
            R1[b] = al1lo; R1[b + 1] = al1hi;
            R2[b]     = c_a2 * (A3lo - A1lo);                  // alpha2
            R2[b + 1] = c_a2 * (A3hi - A1hi);
            A3r[b]     = c_a3 * (A1lo + A3lo) - c_m * al1lo;   // alpha3
            A3r[b + 1] = c_a3 * (A1hi + A3hi) - c_m * al1hi;
        }

        // ---- drain LDS reads, then issue next iteration's staging BEFORE
        //      the compute chain (same slots; now provably consumed) ----
        asm volatile("s_waitcnt lgkmcnt(0)" ::: "memory");
        __builtin_amdgcn_sched_barrier(0);
        if (n + 1 < NI) {
            const int pn = (n + 1) * PPI + pslot;
            const int pc = pn < B ? pn : B - 1;
            stage_all(A4 + (size_t)pc * 48 + q * 4, sb);
        }
        __builtin_amdgcn_sched_barrier(0);

        // ---- C1 = [alpha1, alpha2] into R3 ----
#pragma unroll
        for (int i = 0; i < 8; ++i) R3[i] = (v2f){0.0f, 0.0f};
        mm4<+1>(R3, R1, R2);
        mm4<-1>(R3, R2, R1);

        // ---- T' = (C1 + 2*alpha3)/60 ----
#pragma unroll
        for (int i = 0; i < 8; ++i) {
            const v2f k60 = {1.0f / 60.0f, 1.0f / 60.0f};
            R3[i] = pkfma(R3[i], k60, (1.0f / 30.0f) * A3r[i]);
        }

        // ---- Q = alpha2 - alpha1@T' + T'@alpha1 ----
        mm4<-1>(R2, R1, R3);
        mm4<+1>(R2, R3, R1);

        // ---- P' (R3); Omega0 (R1) ----
#pragma unroll
        for (int i = 0; i < 8; ++i) {
            v2f t0 = R3[i], a10 = R1[i], a3e = A3r[i];
            R3[i] = 0.25f * t0 - (1.0f / 12.0f) * a10 - (1.0f / 80.0f) * a3e;
            R1[i] = a10 + (1.0f / 12.0f) * a3e;
        }

        // ---- Omega = Omega0 + P'@Q - Q@P' ----
        mm4<+1>(R1, R3, R2);
        mm4<-1>(R1, R2, R3);

        // ---- y = expm(Omega) @ y0, Taylor order 6 ----
        float v0 = y0v.x, v1 = y0v.y;
        float yy0 = v0, yy1 = v1;
        const float inv[6] = {1.0f, 0.5f, 1.0f / 3.0f, 0.25f, 0.2f, 1.0f / 6.0f};
#pragma unroll
        for (int k = 0; k < 6; ++k) {
            v2f acc0 = {0.0f, 0.0f}, acc1 = {0.0f, 0.0f};
            v2f vw;
            vw.x = qb<0>(v0); vw.y = qb<0>(v1);
            acc0 = pkfma(R1[0], vw, acc0); acc1 = pkfma(R1[4], vw, acc1);
            vw.x = qb<1>(v0); vw.y = qb<1>(v1);
            acc0 = pkfma(R1[1], vw, acc0); acc1 = pkfma(R1[5], vw, acc1);
            vw.x = qb<2>(v0); vw.y = qb<2>(v1);
            acc0 = pkfma(R1[2], vw, acc0); acc1 = pkfma(R1[6], vw, acc1);
            vw.x = qb<3>(v0); vw.y = qb<3>(v1);
            acc0 = pkfma(R1[3], vw, acc0); acc1 = pkfma(R1[7], vw, acc1);
            v0 = (acc0.x + acc0.y) * inv[k];
            v1 = (acc1.x + acc1.y) * inv[k];
            yy0 += v0;
            yy1 += v1;
        }

        if (p < B)
            *reinterpret_cast<float2*>(out + (size_t)p * 8 + 2 * q) =
                make_float2(yy0, yy1);
    }
}

extern "C" void kernel_launch(void* const* d_in, const int* in_sizes, int n_in,
                              void* d_out, int out_size, void* d_ws, size_t ws_size,
                              hipStream_t stream)
{
    const float* A  = (const float*)d_in[0];
    const float* hp = (const float*)d_in[1];
    const float* y0 = (const float*)d_in[2];
    float* out = (float*)d_out;

    const int B  = in_sizes[2] / 8;          // y0 is (B, 8)
    const int NI = (B + PPI - 1) / PPI;      // pipeline iterations per thread
    magnus6_kernel<<<NBLK, NT, 0, stream>>>(A, hp, y0, out, B, NI);
}

// Round 13
// 24.860 us; speedup vs baseline: 1.2578x; 1.2578x over previous
//
#include <hip/hip_runtime.h>

#define NT 256

// ============================================================================
// FINAL (reverted to best-measured R7 design point, 24.5 us e2e).
// 4 lanes per problem (quad slot q = tid&3 owns global rows {2q, 2q+1} of all
// 8x8 matrices). Cross-lane row fetch = DPP quad_perm broadcast (VALU pipe).
// Matrices stored as column-pairs (v2f); FMAs are packed v_pk_fma_f32.
// alpha3 in a private LDS column (64 B/thread, 16 KB/block, no barriers).
// Live set ~60 floats -> spill-proof at the allocator's 64-VGPR/8-wave point.
//
// Explored and rejected (measured): 1-thread/problem flat (42us), LDS-lean
// variants (allocator spills, 51-63us), 2-lane shfl (145us), coalesced
// (row-parity,col-half) layout (26.7us), y0 hoist (25.0us), persistent
// global_load_lds pipeline at 2 and 3 waves/SIMD (29.1 / 31.3us).
// Zero-reuse workload: LDS staging is pure overhead; 8-wave TLP wins.
// Effective streaming rate ~5.4 TB/s ~ 85% of achievable copy ceiling.
// ============================================================================

typedef float v2f __attribute__((ext_vector_type(2)));

// Broadcast x from quad slot O to all 4 lanes of the quad (quad_perm[O,O,O,O]).
template <int O>
__device__ __forceinline__ float qb(float x) {
    return __int_as_float(__builtin_amdgcn_mov_dpp(
        __float_as_int(x), O * 0x55, 0xF, 0xF, true));
}
template <int O>
__device__ __forceinline__ v2f qb2(v2f y) {
    v2f r;
    r.x = qb<O>(y.x);
    r.y = qb<O>(y.y);
    return r;
}
__device__ __forceinline__ v2f pkfma(v2f a, v2f b, v2f c) {
    return __builtin_elementwise_fma(a, b, c);   // -> v_pk_fma_f32
}

// acc(2x8, col-pairs) += SGN * X(2x8) @ Y, contribution from Y's global rows
// {2O, 2O+1} (held by quad slot O as its local rows 0,1).
template <int SGN, int O>
__device__ __forceinline__ void mm4_o(v2f (&acc)[8], const v2f (&X)[8],
                                      const v2f (&Y)[8]) {
#pragma unroll
    for (int s = 0; s < 2; ++s) {            // global k = 2O + s
        v2f w2[4];
#pragma unroll
        for (int jj = 0; jj < 4; ++jj) w2[jj] = qb2<O>(Y[s * 4 + jj]);
#pragma unroll
        for (int r = 0; r < 2; ++r) {
            // X(row r, col k=2O+s) lives in pair X[r*4+O], component s.
            const float x0 = (s == 0) ? X[r * 4 + O].x : X[r * 4 + O].y;
            const float xs = (SGN > 0) ? x0 : -x0;
            const v2f xx = {xs, xs};
#pragma unroll
            for (int jj = 0; jj < 4; ++jj)
                acc[r * 4 + jj] = pkfma(xx, w2[jj], acc[r * 4 + jj]);
        }
    }
}

template <int SGN>
__device__ __forceinline__ void mm4(v2f (&acc)[8], const v2f (&X)[8],
                                    const v2f (&Y)[8]) {
    mm4_o<SGN, 0>(acc, X, Y);
    mm4_o<SGN, 1>(acc, X, Y);
    mm4_o<SGN, 2>(acc, X, Y);
    mm4_o<SGN, 3>(acc, X, Y);
}

__global__ __launch_bounds__(NT)
void magnus6_kernel(const float* __restrict__ A,
                    const float* __restrict__ hp,
                    const float* __restrict__ y0,
                    float* __restrict__ out,
                    int B)
{
    // alpha3 spill: 4 float4 / thread = 64 B -> 16 KB/block, private column,
    // no barriers; not occupancy-binding.
    __shared__ float4 lds[4][NT];

    const int tx = threadIdx.x;
    const int t  = blockIdx.x * NT + tx;
    const int p  = t >> 2;          // problem index
    const int q  = t & 3;           // quad slot: owns rows 2q, 2q+1
    if (p >= B) return;

    const float h    = hp[0];
    const float c_a2 = h * 1.2909944487358056f;   // h*sqrt(15)/3
    const float c_a3 = h * (10.0f / 3.0f);
    const float c_m  = 20.0f / 3.0f;

    // A is (B,3,8,8). My rows of A1 start at float offset p*192 + q*16.
    const float4* __restrict__ Ap =
        reinterpret_cast<const float4*>(A + (size_t)p * 192 + q * 16);

    v2f R1[8];   // alpha1 -> Omega0 -> Omega
    v2f R2[8];   // alpha2 -> Q (commutator accumulated in place)
    v2f R3[8];   // C1 -> T' -> P'

    // ---- stream-load A1,A2,A3; build alpha1(R1), alpha2(R2), alpha3(LDS) ----
    // chunk c: local row c>>1, cols (c&1)*4 .. +3  -> pairs b, b+1
#pragma unroll
    for (int c = 0; c < 4; ++c) {
        float4 v1 = Ap[c], v2 = Ap[16 + c], v3 = Ap[32 + c];
        const int b = (c >> 1) * 4 + (c & 1) * 2;
        v2f A1lo = {v1.x, v1.y}, A1hi = {v1.z, v1.w};
        v2f A2lo = {v2.x, v2.y}, A2hi = {v2.z, v2.w};
        v2f A3lo = {v3.x, v3.y}, A3hi = {v3.z, v3.w};
        v2f al1lo = h * A2lo, al1hi = h * A2hi;            // alpha1
        R1[b] = al1lo; R1[b + 1] = al1hi;
        R2[b]     = c_a2 * (A3lo - A1lo);                  // alpha2
        R2[b + 1] = c_a2 * (A3hi - A1hi);
        v2f a3lo = c_a3 * (A1lo + A3lo) - c_m * al1lo;     // alpha3
        v2f a3hi = c_a3 * (A1hi + A3hi) - c_m * al1hi;
        lds[c][tx] = make_float4(a3lo.x, a3lo.y, a3hi.x, a3hi.y);
    }

    // ---- C1 = [alpha1, alpha2] into R3 ----
#pragma unroll
    for (int i = 0; i < 8; ++i) R3[i] = (v2f){0.0f, 0.0f};
    mm4<+1>(R3, R1, R2);
    mm4<-1>(R3, R2, R1);

    // ---- T' = (C1 + 2*alpha3)/60 ----
#pragma unroll
    for (int c = 0; c < 4; ++c) {
        float4 v = lds[c][tx];
        v2f a3lo = {v.x, v.y}, a3hi = {v.z, v.w};
        const int b = (c >> 1) * 4 + (c & 1) * 2;
        const v2f k60 = {1.0f / 60.0f, 1.0f / 60.0f};
        R3[b]     = pkfma(R3[b],     k60, (1.0f / 30.0f) * a3lo);
        R3[b + 1] = pkfma(R3[b + 1], k60, (1.0f / 30.0f) * a3hi);
    }

    // ---- Q = alpha2 - alpha1@T' + T'@alpha1  (in place into R2) ----
    mm4<-1>(R2, R1, R3);
    mm4<+1>(R2, R3, R1);

    // ---- P' = T'/4 - alpha1/12 - alpha3/80 (R3); Omega0 = alpha1 + alpha3/12 (R1) ----
#pragma unroll
    for (int c = 0; c < 4; ++c) {
        float4 v = lds[c][tx];
        v2f a3lo = {v.x, v.y}, a3hi = {v.z, v.w};
        const int b = (c >> 1) * 4 + (c & 1) * 2;
        v2f t0 = R3[b], t1 = R3[b + 1];
        v2f a10 = R1[b], a11 = R1[b + 1];
        R3[b]     = 0.25f * t0 - (1.0f / 12.0f) * a10 - (1.0f / 80.0f) * a3lo;
        R3[b + 1] = 0.25f * t1 - (1.0f / 12.0f) * a11 - (1.0f / 80.0f) * a3hi;
        R1[b]     = a10 + (1.0f / 12.0f) * a3lo;
        R1[b + 1] = a11 + (1.0f / 12.0f) * a3hi;
    }

    // ---- Omega = Omega0 + P'@Q - Q@P'  (into R1) ----
    mm4<+1>(R1, R3, R2);
    mm4<-1>(R1, R2, R3);

    // ---- y = expm(Omega) @ y0, Taylor order 6; lane holds y rows 2q,2q+1 ----
    const float2 y0v = *reinterpret_cast<const float2*>(y0 + (size_t)p * 8 + 2 * q);
    float v0 = y0v.x, v1 = y0v.y;
    float yy0 = v0, yy1 = v1;

    const float inv[6] = {1.0f, 0.5f, 1.0f / 3.0f, 0.25f, 0.2f, 1.0f / 6.0f};
#pragma unroll
    for (int k = 0; k < 6; ++k) {
        v2f acc0 = {0.0f, 0.0f}, acc1 = {0.0f, 0.0f};
        // vw[jj] = (v_global[2jj], v_global[2jj+1]) via quad broadcasts
        {
            v2f vw;
            vw.x = qb<0>(v0); vw.y = qb<0>(v1);
            acc0 = pkfma(R1[0], vw, acc0); acc1 = pkfma(R1[4], vw, acc1);
            vw.x = qb<1>(v0); vw.y = qb<1>(v1);
            acc0 = pkfma(R1[1], vw, acc0); acc1 = pkfma(R1[5], vw, acc1);
            vw.x = qb<2>(v0); vw.y = qb<2>(v1);
            acc0 = pkfma(R1[2], vw, acc0); acc1 = pkfma(R1[6], vw, acc1);
            vw.x = qb<3>(v0); vw.y = qb<3>(v1);
            acc0 = pkfma(R1[3], vw, acc0); acc1 = pkfma(R1[7], vw, acc1);
        }
        v0 = (acc0.x + acc0.y) * inv[k];
        v1 = (acc1.x + acc1.y) * inv[k];
        yy0 += v0;
        yy1 += v1;
    }

    *reinterpret_cast<float2*>(out + (size_t)p * 8 + 2 * q) = make_float2(yy0, yy1);
}

extern "C" void kernel_launch(void* const* d_in, const int* in_sizes, int n_in,
                              void* d_out, int out_size, void* d_ws, size_t ws_size,
                              hipStream_t stream)
{
    const float* A  = (const float*)d_in[0];
    const float* hp = (const float*)d_in[1];
    const float* y0 = (const float*)d_in[2];
    float* out = (float*)d_out;

    const int B = in_sizes[2] / 8;        // y0 is (B, 8)
    const int nthreads = 4 * B;           // 4 lanes per problem
    const int grid = (nthreads + NT - 1) / NT;
    magnus6_kernel<<<grid, NT, 0, stream>>>(A, hp, y0, out, B);
}